// Round 1
// baseline (112.051 us; speedup 1.0000x reference)
//
#include <hip/hip_runtime.h>
#include <hip/hip_bf16.h>

#define NUM_AGES 100
#define FEAT 512
#define BATCH 4096
#define EPSF 1e-6f
#define INV_T 10.0f
#define INV_NORM (1.0f / ((float)BATCH * (float)(BATCH - 1)))

#define BM 128
#define BN 64
#define BK 64
// kept tiles: bx >= 2*by, by in [0,32), bx in [0,64) -> sum(64-2*by) = 1056
#define NTILES 1056
#define NXCD 8
#define CHUNK (NTILES / NXCD)   // 132, NTILES % 8 == 0 -> bijective XCD swizzle

typedef __bf16 bf16_t;
typedef __bf16 v8bf __attribute__((ext_vector_type(8)));
typedef float v4f __attribute__((ext_vector_type(4)));

// async global->LDS, 16B per lane; LDS dest is wave-uniform base + lane*16
__device__ __forceinline__ void async16(const void* g, void* l) {
  __builtin_amdgcn_global_load_lds(
      (const __attribute__((address_space(1))) void*)g,
      (__attribute__((address_space(3))) void*)l, 16, 0, 0);
}

// ---------------- kernel 1: per-sample prep (inline rank + pre-swizzle) ---
// Block j computes rank(j) = #{k: a_k < a_j or (a_k==a_j and k<j)} (stable,
// bijective) and writes to sorted position `rank`. zb/wb are stored
// XOR-swizzled: within each 128B (64-elem) K-slab, logical 16B granule g of
// row r sits at physical position g ^ (r&7). pair_kernel's contiguous
// global_load_lds staging then lands a bank-balanced LDS layout (2 lanes per
// bank-quad = free) with zero change to its global access pattern.
__global__ __launch_bounds__(256) void prep_kernel(
    const float* __restrict__ z, const int* __restrict__ ages,
    const float* __restrict__ proxies,
    bf16_t* __restrict__ zb, bf16_t* __restrict__ wb,
    float* __restrict__ sq, float* __restrict__ hd,
    int* __restrict__ ages_s, float* __restrict__ out)
{
  int j = blockIdx.x;          // original sample index
  int t = threadIdx.x;
  if (j == 0 && t == 0) out[0] = 0.0f;   // pair_kernel accumulates into out

  int araw = ages[j];
  int a = araw < 0 ? 0 : (araw > NUM_AGES - 1 ? NUM_AGES - 1 : araw);
  const float* cc = proxies + (size_t)a * FEAT;
  const float* cn = proxies + (size_t)(a + 1 > NUM_AGES - 1 ? NUM_AGES - 1 : a + 1) * FEAT;
  const float* cp = proxies + (size_t)(a - 1 < 0 ? 0 : a - 1) * FEAT;
  const float* zr = z + (size_t)j * FEAT;

  // ---- rank of sample j in stable age order ----
  int cnt = 0;
#pragma unroll
  for (int e = 0; e < BATCH / 256; ++e) {
    int k = t + e * 256;
    int ak = ages[k];
    cnt += (ak < araw || (ak == araw && k < j)) ? 1 : 0;
  }

  // ---- vectorized per-sample math: thread t owns cols 2t, 2t+1 ----
  int c0 = 2 * t;
  float2 cc2 = *(const float2*)(cc + c0);
  float2 cn2 = *(const float2*)(cn + c0);
  float2 cp2 = *(const float2*)(cp + c0);
  float2 z2  = *(const float2*)(zr + c0);
  float df0 = cn2.x - cc2.x, df1 = cn2.y - cc2.y;
  float db0 = cp2.x - cc2.x, db1 = cp2.y - cc2.y;
  float s_ff = df0 * df0 + df1 * df1;
  float s_bb = db0 * db0 + db1 * db1;
  float s_zz = z2.x * z2.x + z2.y * z2.y;
  float s_zf = z2.x * df0 + z2.y * df1;
  float s_zb = z2.x * db0 + z2.y * db1;

  float fcnt = (float)cnt;
#pragma unroll
  for (int off = 32; off > 0; off >>= 1) {
    s_ff += __shfl_down(s_ff, off, 64);
    s_bb += __shfl_down(s_bb, off, 64);
    s_zz += __shfl_down(s_zz, off, 64);
    s_zf += __shfl_down(s_zf, off, 64);
    s_zb += __shfl_down(s_zb, off, 64);
    fcnt += __shfl_down(fcnt, off, 64);
  }
  __shared__ float red[4][6];
  int wv = t >> 6, lane = t & 63;
  if (lane == 0) {
    red[wv][0] = s_ff; red[wv][1] = s_bb; red[wv][2] = s_zz;
    red[wv][3] = s_zf; red[wv][4] = s_zb; red[wv][5] = fcnt;
  }
  __syncthreads();
  float ff = red[0][0] + red[1][0] + red[2][0] + red[3][0];
  float bb = red[0][1] + red[1][1] + red[2][1] + red[3][1];
  float zz = red[0][2] + red[1][2] + red[2][2] + red[3][2];
  float zdf = red[0][3] + red[1][3] + red[2][3] + red[3][3];
  float zdb = red[0][4] + red[1][4] + red[2][4] + red[3][4];
  int rank = (int)(red[0][5] + red[1][5] + red[2][5] + red[3][5]);

  float rf = 1.0f / (sqrtf(ff) + EPSF);
  float rb = 1.0f / (sqrtf(bb) + EPSF);
  int key = rank & 7;
  // swizzled column for the granule holding cols {2t, 2t+1}
  int c2s = (c0 & ~63) | (((((c0 >> 3) & 7) ^ key) << 3)) | (c0 & 7);
  float w0 = db0 * rb - df0 * rf;
  float w1 = db1 * rb - df1 * rf;
  union { bf16_t h[2]; unsigned u; } uz, uw;
  uz.h[0] = (bf16_t)z2.x; uz.h[1] = (bf16_t)z2.y;
  uw.h[0] = (bf16_t)w0;   uw.h[1] = (bf16_t)w1;
  *(unsigned*)((char*)zb + ((size_t)rank * FEAT + c2s) * 2) = uz.u;
  *(unsigned*)((char*)wb + ((size_t)rank * FEAT + c2s) * 2) = uw.u;
  if (t == 0) {
    sq[rank] = zz;
    hd[rank] = rb * zdb - rf * zdf;
    ages_s[rank] = araw;
  }
}

// ---------------- kernel 2: fused pairwise tile (upper-tri band only) ----
// Age-sorted samples; tiles with i_min >= j_max+1 contribute 0 -> skipped.
// v2: (a) double-buffered LDS + single barrier per K-step: stage tile t+1
//     while MFMAing tile t, so the barrier's implicit vmcnt(0) waits on
//     loads issued a full compute-phase (~400cy) earlier instead of
//     serializing issue->L3-latency->compute each step (was 93% stall:
//     occupancy counter gave ~44K cy avg wave lifetime vs ~3K cy of work).
// (b) XCD-chunked supertile order: 8x8 supertiles, NTILES=8*132 bijective
//     chunking -> each XCD's concurrent tiles share ~2MB of A/Z/W panels,
//     fitting its private 4MB L2 (zb+wb = 8MB does NOT fit; round-robin
//     dispatch previously forced staging to L3, ~600-900cy latency).
// LDS 2x32K + aux ~= 67KB -> 2 blocks/CU; launch_bounds(256,2).
__global__ __launch_bounds__(256, 2) void pair_kernel(
    const bf16_t* __restrict__ zb, const bf16_t* __restrict__ wb,
    const float* __restrict__ sq, const float* __restrict__ hd,
    const int* __restrict__ ages, float* __restrict__ out)
{
  // per buffer: A 128x64 bf16 = 16384 B | Z: 64x64 = 8192 B | W: 64x64 = 8192 B
  __shared__ __attribute__((aligned(16))) char lds[2][32768];
  __shared__ float s_sqi[BM];
  __shared__ int   s_agei[BM];
  __shared__ float s_sqj[BN];
  __shared__ float s_hdj[BN];
  __shared__ int   s_agej[BN];
  __shared__ float wsum[4];

  int t = threadIdx.x;
  int wv = t >> 6, lane = t & 63;

  // ---- tile decode: XCD chunk (blockIdx%8 -> XCD) + 8x8 supertile walk ----
  // tile_id in [0,NTILES); supertiles enumerated row-major (sy,sx), tiles
  // within a supertile by-major. Chunk x = tile_ids [132x,132x+132) -> ~2
  // adjacent supertiles -> concurrent per-XCD working set ~2MB (L2-resident).
  int by = 0, bx = 0;
  {
    int rem = (blockIdx.x & 7) * CHUNK + (blockIdx.x >> 3);
    int done = 0;
    for (int sy = 0; sy < 4 && !done; ++sy) {
      for (int sx = 0; sx < 8 && !done; ++sx) {
        int cnt = 0;
        for (int r = 0; r < 8; ++r) {
          int b = 8 * sy + r;
          int lo = 2 * b; if (lo < 8 * sx) lo = 8 * sx;
          int ww = 8 * sx + 8 - lo; if (ww < 0) ww = 0;
          cnt += ww;
        }
        if (rem < cnt) {
          for (int r = 0; r < 8 && !done; ++r) {
            int b = 8 * sy + r;
            int lo = 2 * b; if (lo < 8 * sx) lo = 8 * sx;
            int ww = 8 * sx + 8 - lo; if (ww < 0) ww = 0;
            if (rem < ww) { by = b; bx = lo + rem; done = 1; }
            else rem -= ww;
          }
        } else {
          rem -= cnt;
        }
      }
    }
  }
  int i0 = by * BM, j0 = bx * BN;

  if (t < BM) {
    s_sqi[t] = sq[i0 + t];
    s_agei[t] = ages[i0 + t];
  } else if (t < BM + BN) {
    int u = t - BM;
    s_sqj[u] = sq[j0 + u];
    s_hdj[u] = hd[j0 + u];
    s_agej[u] = ages[j0 + u];
  }

  v4f accG[4][2], accH[4][2];
#pragma unroll
  for (int a = 0; a < 4; ++a)
#pragma unroll
    for (int b = 0; b < 2; ++b) {
      accG[a][b] = (v4f){0.f, 0.f, 0.f, 0.f};
      accH[a][b] = (v4f){0.f, 0.f, 0.f, 0.f};
    }

  int wm = wv >> 1, wn = wv & 1;        // wave grid 2x2: 64 rows x 32 cols each
  int lm = lane & 15, q = lane >> 4;
  // swizzled granule byte offsets for the two 32-elem slabs (key = lm&7)
  int psw0 = ((q     ) ^ (lm & 7)) * 16;
  int psw1 = ((q + 4 ) ^ (lm & 7)) * 16;

  // staging: per async16, lane l covers row (l>>3), physical granule (l&7)
  // of an 8-row x 128B chunk (contiguous copy preserves prep's swizzle).
  int loff = (lane >> 3) * FEAT + (lane & 7) * 8;   // bf16 elements
  const bf16_t* baseA = zb + (size_t)i0 * FEAT + loff;
  const bf16_t* baseZ = zb + (size_t)j0 * FEAT + loff;
  const bf16_t* baseW = wb + (size_t)j0 * FEAT + loff;

  // ---- prologue: stage K-tile 0 into buf 0 ----
#pragma unroll
  for (int c = 0; c < 4; ++c) {
    int chunk = wv * 4 + c;
    async16(baseA + (size_t)chunk * 8 * FEAT, lds[0] + chunk * 1024);
  }
#pragma unroll
  for (int c = 0; c < 2; ++c) {
    int chunk = wv * 2 + c;
    async16(baseZ + (size_t)chunk * 8 * FEAT, lds[0] + 16384 + chunk * 1024);
    async16(baseW + (size_t)chunk * 8 * FEAT, lds[0] + 24576 + chunk * 1024);
  }
  __syncthreads();   // implicit vmcnt(0): buf0 ready

  int cur = 0;
  for (int it = 0; it < FEAT / BK; ++it) {
    // stage NEXT K-tile into the other buffer (issued before compute so the
    // end-of-iter barrier's vmcnt(0) drain overlaps with ds_read+MFMA below)
    if (it + 1 < FEAT / BK) {
      int k0n = (it + 1) * BK;
      char* nb = lds[cur ^ 1];
#pragma unroll
      for (int c = 0; c < 4; ++c) {
        int chunk = wv * 4 + c;
        async16(baseA + (size_t)chunk * 8 * FEAT + k0n, nb + chunk * 1024);
      }
#pragma unroll
      for (int c = 0; c < 2; ++c) {
        int chunk = wv * 2 + c;
        async16(baseZ + (size_t)chunk * 8 * FEAT + k0n, nb + 16384 + chunk * 1024);
        async16(baseW + (size_t)chunk * 8 * FEAT + k0n, nb + 24576 + chunk * 1024);
      }
    }

    const char* cb = lds[cur];
#pragma unroll
    for (int s = 0; s < 2; ++s) {
      int psw = s ? psw1 : psw0;
      v8bf afr[4], bz[2], bw[2];
#pragma unroll
      for (int mi = 0; mi < 4; ++mi) {
        int r = wm * 64 + mi * 16 + lm;
        afr[mi] = *(const v8bf*)(cb + r * 128 + psw);
      }
#pragma unroll
      for (int ni = 0; ni < 2; ++ni) {
        int r = wn * 32 + ni * 16 + lm;
        bz[ni] = *(const v8bf*)(cb + 16384 + r * 128 + psw);
        bw[ni] = *(const v8bf*)(cb + 24576 + r * 128 + psw);
      }
#pragma unroll
      for (int mi = 0; mi < 4; ++mi)
#pragma unroll
        for (int ni = 0; ni < 2; ++ni) {
          accG[mi][ni] = __builtin_amdgcn_mfma_f32_16x16x32_bf16(afr[mi], bz[ni], accG[mi][ni], 0, 0, 0);
          accH[mi][ni] = __builtin_amdgcn_mfma_f32_16x16x32_bf16(afr[mi], bw[ni], accH[mi][ni], 0, 0, 0);
        }
    }

    if (it + 1 < FEAT / BK) {
      __syncthreads();   // drains this iter's stage loads; next buf ready
      cur ^= 1;
    }
  }

  // epilogue: C/D layout col = lane&15 (-> j), row = q*4 + reg (-> i)
  float tsum = 0.f;
#pragma unroll
  for (int ni = 0; ni < 2; ++ni) {
    int jl = wn * 32 + ni * 16 + lm;
    float sqj = s_sqj[jl];
    float hdj = s_hdj[jl];
    int aj = s_agej[jl];
#pragma unroll
    for (int mi = 0; mi < 4; ++mi) {
#pragma unroll
      for (int r = 0; r < 4; ++r) {
        int il = wm * 64 + mi * 16 + q * 4 + r;
        float g = accG[mi][ni][r];
        float h = accH[mi][ni][r];
        float d2 = fmaxf(s_sqi[il] + sqj - 2.0f * g, 1e-12f);
        float rs = __builtin_amdgcn_rsqf(d2);
        float arg = (h - hdj) * INV_T * rs;
        float sp = fmaxf(arg, 0.0f) + __logf(1.0f + __expf(-fabsf(arg)));
        tsum += (s_agei[il] < aj) ? sp : 0.0f;
      }
    }
  }

#pragma unroll
  for (int off = 32; off > 0; off >>= 1) tsum += __shfl_down(tsum, off, 64);
  if (lane == 0) wsum[wv] = tsum;
  __syncthreads();
  if (t == 0)
    atomicAdd(out, (wsum[0] + wsum[1] + wsum[2] + wsum[3]) * INV_NORM);
}

extern "C" void kernel_launch(void* const* d_in, const int* in_sizes, int n_in,
                              void* d_out, int out_size, void* d_ws, size_t ws_size,
                              hipStream_t stream) {
  const float* z = (const float*)d_in[0];
  const int* ages = (const int*)d_in[1];
  const float* proxies = (const float*)d_in[2];
  float* out = (float*)d_out;

  char* ws = (char*)d_ws;
  bf16_t* zb = (bf16_t*)ws;                                   // 4 MB
  bf16_t* wb = (bf16_t*)(ws + (size_t)4 * 1024 * 1024);       // 4 MB
  size_t o = (size_t)8 * 1024 * 1024;
  float* sq      = (float*)(ws + o);            // 16 KB
  float* hd      = (float*)(ws + o + 16384);    // 16 KB
  int*   ages_s  = (int*)  (ws + o + 32768);    // 16 KB

  prep_kernel<<<BATCH, 256, 0, stream>>>(z, ages, proxies, zb, wb, sq, hd, ages_s, out);
  pair_kernel<<<NTILES, 256, 0, stream>>>(zb, wb, sq, hd, ages_s, out);
}